// Round 5
// baseline (281.157 us; speedup 1.0000x reference)
//
#include <hip/hip_runtime.h>

// ---------------------------------------------------------------------------
// SAM vision attention (B=1, H=W=64, C=768, 12 heads x hd=64). fp32 I/O.
// cvt -> QKV proj (128-tile) -> rel_w -> flash attn (rel_h fused) -> out proj
// MFMA v_mfma_f32_16x16x32_bf16 layouts (guide-verified m89/m91):
//   A/B frag: [m|n = lane&15][k = (lane>>4)*8 + j]   (8 bf16 / lane, b128)
//   C/D     : col = lane&15, row = (lane>>4)*4 + reg (4 f32 / lane)
// R5: attn double-buffers K/V with raw s_barrier + s_waitcnt vmcnt(4) (the
// compiler's __syncthreads vmcnt(0) would drain the prefetch); rel_h computed
// in-kernel (8 MFMA on register-resident Q + gathered Rh rows) and broadcast
// per tile via __shfl; P split by key-halves with V token-permutation
// sc(kk) = ((kk>>4)>>1)*32 + (kk&15)*2 + ((kk>>4)&1), shrinking spb to 5 KB.
// ---------------------------------------------------------------------------

typedef __attribute__((ext_vector_type(8))) short bf16x8;
typedef __attribute__((ext_vector_type(4))) float f32x4;
typedef __attribute__((ext_vector_type(4))) short s16x4;

__device__ __forceinline__ float b2f(unsigned short h) {
    union { unsigned int u; float f; } v; v.u = ((unsigned int)h) << 16; return v.f;
}
__device__ __forceinline__ unsigned short f2b(float f) {
    union { float f; unsigned int u; } v; v.f = f;
    unsigned int r = v.u + 0x7FFFu + ((v.u >> 16) & 1u);  // RNE
    return (unsigned short)(r >> 16);
}
__device__ __forceinline__ void gl_lds16(const void* g, void* l) {
    __builtin_amdgcn_global_load_lds(
        (const __attribute__((address_space(1))) void*)g,
        (__attribute__((address_space(3))) void*)l, 16, 0, 0);
}

// ---------------------------------------------------------------------------
// fp32 -> bf16 bulk convert into one contiguous region (quad-indexed).
// ---------------------------------------------------------------------------
__global__ __launch_bounds__(256) void cvt_bf16(
        const float* __restrict__ hs, const float* __restrict__ wq,
        const float* __restrict__ wk, const float* __restrict__ wv,
        const float* __restrict__ wo, const float* __restrict__ rph,
        const float* __restrict__ rpw, unsigned short* __restrict__ dst) {
    const int idx = blockIdx.x * 256 + threadIdx.x;
    if (idx >= 1380320) return;
    const float* src;
    int off;
    if      (idx < 786432)  { src = hs;  off = idx; }
    else if (idx < 933888)  { src = wq;  off = idx - 786432; }
    else if (idx < 1081344) { src = wk;  off = idx - 933888; }
    else if (idx < 1228800) { src = wv;  off = idx - 1081344; }
    else if (idx < 1376256) { src = wo;  off = idx - 1228800; }
    else if (idx < 1378288) { src = rph; off = idx - 1376256; }
    else                    { src = rpw; off = idx - 1378288; }
    const float4 v = ((const float4*)src)[off];
    s16x4 o;
    o[0] = (short)f2b(v.x); o[1] = (short)f2b(v.y);
    o[2] = (short)f2b(v.z); o[3] = (short)f2b(v.w);
    *(s16x4*)(dst + (size_t)idx * 4) = o;
}

// ---------------------------------------------------------------------------
// Fused QKV projection, 128x128 tile. M=4096, N=768 per z, K=768, BK=32.
// z: 0->q [n>>6][m][n&63], 1->k same, 2->v^T with token permutation
// sc(kk) = ((kk>>4)>>1)*32 + (kk&15)*2 + ((kk>>4)&1) within each 64-tile.
// ---------------------------------------------------------------------------
__launch_bounds__(256, 3)
__global__ void qkv128(const unsigned short* __restrict__ X,
                       const unsigned short* __restrict__ Wq,
                       const unsigned short* __restrict__ Wk,
                       const unsigned short* __restrict__ Wv,
                       const float* __restrict__ bq,
                       const float* __restrict__ bk,
                       const float* __restrict__ bv,
                       unsigned short* __restrict__ qb,
                       unsigned short* __restrict__ kb,
                       unsigned short* __restrict__ vtb) {
    __shared__ __align__(16) unsigned short abuf[4 * 128 * 8];
    __shared__ __align__(16) unsigned short bbuf[4 * 128 * 8];
    const int tid = threadIdx.x, lane = tid & 63, w = tid >> 6;
    const int r = lane & 15, quad = lane >> 4;
    const int nt = blockIdx.x, mt = blockIdx.y, z = blockIdx.z;
    const unsigned short* W  = (z == 0) ? Wq : (z == 1) ? Wk : Wv;
    const float*          Bv = (z == 0) ? bq : (z == 1) ? bk : bv;
    unsigned short*     outp = (z == 0) ? qb : (z == 1) ? kb : vtb;

    const int c0 = w * 64 + lane, c1 = c0 + 256;
    const unsigned short* xs0 = X + (mt * 128 + (c0 & 127)) * 768 + (c0 >> 7) * 8;
    const unsigned short* xs1 = X + (mt * 128 + (c1 & 127)) * 768 + (c1 >> 7) * 8;
    const unsigned short* ws0 = W + (nt * 128 + (c0 & 127)) * 768 + (c0 >> 7) * 8;
    const unsigned short* ws1 = W + (nt * 128 + (c1 & 127)) * 768 + (c1 >> 7) * 8;

    const int wr = (w & 1) * 64, wc = (w >> 1) * 64;
    f32x4 acc[4][4] = {};
    for (int kt = 0; kt < 24; ++kt) {
        gl_lds16(xs0 + kt * 32, &abuf[w * 512]);
        gl_lds16(xs1 + kt * 32, &abuf[2048 + w * 512]);
        gl_lds16(ws0 + kt * 32, &bbuf[w * 512]);
        gl_lds16(ws1 + kt * 32, &bbuf[2048 + w * 512]);
        __syncthreads();
        bf16x8 af[4], bfr[4];
#pragma unroll
        for (int i = 0; i < 4; ++i)
            af[i] = *(const bf16x8*)&abuf[(quad * 128 + wr + i * 16 + r) * 8];
#pragma unroll
        for (int j = 0; j < 4; ++j)
            bfr[j] = *(const bf16x8*)&bbuf[(quad * 128 + wc + j * 16 + r) * 8];
#pragma unroll
        for (int i = 0; i < 4; ++i)
#pragma unroll
            for (int j = 0; j < 4; ++j)
                acc[i][j] = __builtin_amdgcn_mfma_f32_16x16x32_bf16(af[i], bfr[j], acc[i][j], 0, 0, 0);
        __syncthreads();
    }
#pragma unroll
    for (int j = 0; j < 4; ++j) {
        const int n = nt * 128 + wc + j * 16 + r;
        const float bias = Bv[n];
        const int nhi = n >> 6, nlo = n & 63;
#pragma unroll
        for (int i = 0; i < 4; ++i) {
#pragma unroll
            for (int reg = 0; reg < 4; ++reg) {
                const unsigned short hv = f2b(acc[i][j][reg] + bias);
                if (z < 2) {
                    const int m = mt * 128 + wr + i * 16 + quad * 4 + reg;
                    outp[(nhi * 4096 + m) * 64 + nlo] = hv;
                } else {
                    // kk = i*16 + (quad*4+reg); sc = (i>>1)*32 + (quad*4+reg)*2 + (i&1)
                    const int mp = mt * 128 + wr + (i >> 1) * 32 + (quad * 4 + reg) * 2 + (i & 1);
                    outp[(nhi * 64 + nlo) * 4096 + mp] = hv;
                }
            }
        }
    }
}

// ---------------------------------------------------------------------------
// Output projection, 128x128 tile, fp32 row-major out. M=4096, N=768, K=768.
// ---------------------------------------------------------------------------
__launch_bounds__(256, 3)
__global__ void out128(const unsigned short* __restrict__ X,
                       const unsigned short* __restrict__ W,
                       const float* __restrict__ Bv,
                       float* __restrict__ out) {
    __shared__ __align__(16) unsigned short abuf[4 * 128 * 8];
    __shared__ __align__(16) unsigned short bbuf[4 * 128 * 8];
    const int tid = threadIdx.x, lane = tid & 63, w = tid >> 6;
    const int r = lane & 15, quad = lane >> 4;
    const int nt = blockIdx.x, mt = blockIdx.y;

    const int c0 = w * 64 + lane, c1 = c0 + 256;
    const unsigned short* xs0 = X + (mt * 128 + (c0 & 127)) * 768 + (c0 >> 7) * 8;
    const unsigned short* xs1 = X + (mt * 128 + (c1 & 127)) * 768 + (c1 >> 7) * 8;
    const unsigned short* ws0 = W + (nt * 128 + (c0 & 127)) * 768 + (c0 >> 7) * 8;
    const unsigned short* ws1 = W + (nt * 128 + (c1 & 127)) * 768 + (c1 >> 7) * 8;

    const int wr = (w & 1) * 64, wc = (w >> 1) * 64;
    f32x4 acc[4][4] = {};
    for (int kt = 0; kt < 24; ++kt) {
        gl_lds16(xs0 + kt * 32, &abuf[w * 512]);
        gl_lds16(xs1 + kt * 32, &abuf[2048 + w * 512]);
        gl_lds16(ws0 + kt * 32, &bbuf[w * 512]);
        gl_lds16(ws1 + kt * 32, &bbuf[2048 + w * 512]);
        __syncthreads();
        bf16x8 af[4], bfr[4];
#pragma unroll
        for (int i = 0; i < 4; ++i)
            af[i] = *(const bf16x8*)&abuf[(quad * 128 + wr + i * 16 + r) * 8];
#pragma unroll
        for (int j = 0; j < 4; ++j)
            bfr[j] = *(const bf16x8*)&bbuf[(quad * 128 + wc + j * 16 + r) * 8];
#pragma unroll
        for (int i = 0; i < 4; ++i)
#pragma unroll
            for (int j = 0; j < 4; ++j)
                acc[i][j] = __builtin_amdgcn_mfma_f32_16x16x32_bf16(af[i], bfr[j], acc[i][j], 0, 0, 0);
        __syncthreads();
    }
#pragma unroll
    for (int j = 0; j < 4; ++j) {
        const int n = nt * 128 + wc + j * 16 + r;
        const float bias = Bv[n];
#pragma unroll
        for (int i = 0; i < 4; ++i) {
#pragma unroll
            for (int reg = 0; reg < 4; ++reg) {
                const int m = mt * 128 + wr + i * 16 + quad * 4 + reg;
                out[m * 768 + n] = acc[i][j][reg] + bias;
            }
        }
    }
}

// ---------------------------------------------------------------------------
// rel_w only (rel_h is fused into attn): per (head, a=query-col) 64x64x64
// GEMM; queries t = m*64 + a, B[n][c] = rpw[a - n + 63][c].
// ---------------------------------------------------------------------------
__launch_bounds__(256, 4)
__global__ void relw(const unsigned short* __restrict__ qbuf,
                     const unsigned short* __restrict__ rpw,
                     unsigned short* __restrict__ rw) {
    __shared__ __align__(16) unsigned short abuf[8 * 64 * 8];
    __shared__ __align__(16) unsigned short bbuf[8 * 64 * 8];
    const int tid = threadIdx.x;
    const int lane = tid & 63, w = tid >> 6;
    const int r = lane & 15, quad = lane >> 4;
    const int a = blockIdx.x, h = blockIdx.y;

#pragma unroll
    for (int gg = 0; gg < 2; ++gg) {
        const int g = w * 2 + gg;
        gl_lds16(qbuf + (h * 4096 + lane * 64 + a) * 64 + g * 8, &abuf[g * 512]);
        gl_lds16(rpw + (a - lane + 63) * 64 + g * 8, &bbuf[g * 512]);
    }
    __syncthreads();

    f32x4 acc[4] = {};
#pragma unroll
    for (int s = 0; s < 2; ++s) {
        bf16x8 af = *(const bf16x8*)&abuf[((s * 4 + quad) * 64 + w * 16 + r) * 8];
#pragma unroll
        for (int j = 0; j < 4; ++j) {
            bf16x8 bfr = *(const bf16x8*)&bbuf[((s * 4 + quad) * 64 + j * 16 + r) * 8];
            acc[j] = __builtin_amdgcn_mfma_f32_16x16x32_bf16(af, bfr, acc[j], 0, 0, 0);
        }
    }
#pragma unroll
    for (int j = 0; j < 4; ++j) {
#pragma unroll
        for (int reg = 0; reg < 4; ++reg) {
            const int m = w * 16 + quad * 4 + reg, n = j * 16 + r;
            rw[((h * 4096 + m * 64 + a)) * 64 + n] = f2b(acc[j][reg]);
        }
    }
}

// ---------------------------------------------------------------------------
// Flash attention, 64-query tile (4 waves x 16 q), 64 key tiles of 64.
// Double-buffered K/V staging with raw barriers + vmcnt(4). rel_h computed
// in-kernel (block's queries share image-row qt). Fixed softmax ref (m=0).
// P written per key-half (32 keys) into a 40-stride wave-private buffer.
// ---------------------------------------------------------------------------
__launch_bounds__(256, 3)
__global__ void attn(const unsigned short* __restrict__ qbuf,
                     const unsigned short* __restrict__ kbuf,
                     const unsigned short* __restrict__ vtbuf,
                     const unsigned short* __restrict__ rph,
                     const unsigned short* __restrict__ rw,
                     unsigned short* __restrict__ aout) {
    __shared__ __align__(16) unsigned short skb[2][4096];  // K [d_oct][key][8]
    __shared__ __align__(16) unsigned short svb[2][4096];  // V^T [scol_oct][d][8]
    __shared__ __align__(16) unsigned short spb[4 * 16 * 40];  // P half, stride 40
    const int tid = threadIdx.x;
    const int lane = tid & 63, w = tid >> 6;
    const int r = lane & 15, quad = lane >> 4;
    const int qt = blockIdx.x, h = blockIdx.y;
    const float L2E = 1.44269504f;
    const float SC = 0.125f * L2E;

    // ---- prologue: Q frags, rel_w regs, rel_h via MFMA on gathered Rh rows
    bf16x8 qf[2];
    const unsigned short* qrow = qbuf + (h * 4096 + qt * 64 + w * 16 + r) * 64;
    qf[0] = *(const bf16x8*)(qrow + quad * 8);
    qf[1] = *(const bf16x8*)(qrow + 32 + quad * 8);

    float rwL[4][4];  // rel_w * log2e (kj = key%64 is tile-invariant)
    {
        const unsigned short* rwrow = rw + (h * 4096 + qt * 64) * 64;
#pragma unroll
        for (int reg = 0; reg < 4; ++reg) {
            const int ql = w * 16 + quad * 4 + reg;
#pragma unroll
            for (int j = 0; j < 4; ++j)
                rwL[j][reg] = b2f(rwrow[ql * 64 + j * 16 + r]) * L2E;
        }
    }
    // gather Rh rows (ki = lane -> rph[qt - ki + 63]) into svb[0] as [c_oct][ki][8]
#pragma unroll
    for (int gg = 0; gg < 2; ++gg) {
        const int g = w * 2 + gg;
        gl_lds16(rph + (qt - lane + 63) * 64 + g * 8, &svb[0][g * 512]);
    }
    __syncthreads();
    float rhs[4][4];  // [ki>>4][reg]: rel_h(this wave's q rows, ki=j*16+r) * L2E
    {
        f32x4 ra[4] = {};
#pragma unroll
        for (int s2 = 0; s2 < 2; ++s2) {
#pragma unroll
            for (int j = 0; j < 4; ++j) {
                bf16x8 rf = *(const bf16x8*)&svb[0][((s2 * 4 + quad) * 64 + j * 16 + r) * 8];
                ra[j] = __builtin_amdgcn_mfma_f32_16x16x32_bf16(qf[s2], rf, ra[j], 0, 0, 0);
            }
        }
#pragma unroll
        for (int j = 0; j < 4; ++j)
#pragma unroll
            for (int reg = 0; reg < 4; ++reg) rhs[j][reg] = ra[j][reg] * L2E;
    }
    __syncthreads();  // all waves done with svb[0] before stage(0) overwrites

    // ---- stage tile 0 into buffer 0
#pragma unroll
    for (int gg = 0; gg < 2; ++gg) {
        const int g = w * 2 + gg;
        gl_lds16(kbuf + (h * 4096 + lane) * 64 + g * 8, &skb[0][g * 512]);
        gl_lds16(vtbuf + (h * 64 + lane) * 4096 + g * 8, &svb[0][g * 512]);
    }

    float lsum[4] = {0.f, 0.f, 0.f, 0.f};
    f32x4 oacc[4] = {};

    // ---- main loop: t = th*16 + tl
#pragma unroll
    for (int th = 0; th < 4; ++th) {
#pragma unroll 1
        for (int tl = 0; tl < 16; ++tl) {
            const int t = th * 16 + tl;
            const int tp = (t + 1) & 63;     // prefetch tile (t=63 redundantly re-stages 0)
            const int bc = t & 1, bn = bc ^ 1;
            // prefetch t+1 into the other buffer
#pragma unroll
            for (int gg = 0; gg < 2; ++gg) {
                const int g = w * 2 + gg;
                gl_lds16(kbuf + (h * 4096 + tp * 64 + lane) * 64 + g * 8, &skb[bn][g * 512]);
                gl_lds16(vtbuf + (h * 64 + lane) * 4096 + tp * 64 + g * 8, &svb[bn][g * 512]);
            }
            // wait only for tile t's 4 loads (the 4 just issued stay in flight)
            asm volatile("s_waitcnt vmcnt(4)\n\ts_barrier" ::: "memory");

            // S = Q K^T (16 q x 64 k per wave)
            f32x4 sacc[4] = {};
#pragma unroll
            for (int s2 = 0; s2 < 2; ++s2) {
#pragma unroll
                for (int j = 0; j < 4; ++j) {
                    bf16x8 kf = *(const bf16x8*)&skb[bc][((s2 * 4 + quad) * 64 + j * 16 + r) * 8];
                    sacc[j] = __builtin_amdgcn_mfma_f32_16x16x32_bf16(qf[s2], kf, sacc[j], 0, 0, 0);
                }
            }
            // rel_h bias for key row t: broadcast from lane (quad*16 + tl)
            float bh[4];
#pragma unroll
            for (int reg = 0; reg < 4; ++reg)
                bh[reg] = __shfl(rhs[th][reg], quad * 16 + tl, 64);

            // softmax + PV per 32-key half
#pragma unroll
            for (int s = 0; s < 2; ++s) {
#pragma unroll
                for (int reg = 0; reg < 4; ++reg) {
                    const float p0 = exp2f(fmaf(sacc[2 * s][reg], SC, bh[reg] + rwL[2 * s][reg]));
                    const float p1 = exp2f(fmaf(sacc[2 * s + 1][reg], SC, bh[reg] + rwL[2 * s + 1][reg]));
                    lsum[reg] += p0 + p1;
                    union { float f; unsigned int u; } c0, c1;
                    c0.f = p0; c1.f = p1;
                    const unsigned int pk = __builtin_amdgcn_perm(c1.u, c0.u, 0x07060302);
                    *(unsigned int*)&spb[w * 640 + (quad * 4 + reg) * 40 + r * 2] = pk;
                }
                bf16x8 pf = *(const bf16x8*)&spb[w * 640 + r * 40 + quad * 8];
#pragma unroll
                for (int j = 0; j < 4; ++j) {
                    bf16x8 vf = *(const bf16x8*)&svb[bc][((s * 4 + quad) * 64 + j * 16 + r) * 8];
                    oacc[j] = __builtin_amdgcn_mfma_f32_16x16x32_bf16(pf, vf, oacc[j], 0, 0, 0);
                }
            }
            // all waves done reading buffer bc before next iter overwrites it
            asm volatile("s_barrier" ::: "memory");
        }
    }
    // ---- epilogue: deferred l reduction + normalize + store
#pragma unroll
    for (int reg = 0; reg < 4; ++reg) {
        float s = lsum[reg];
        s += __shfl_xor(s, 1);
        s += __shfl_xor(s, 2);
        s += __shfl_xor(s, 4);
        s += __shfl_xor(s, 8);
        const float inv = 1.f / s;
        const int m = qt * 64 + w * 16 + quad * 4 + reg;
#pragma unroll
        for (int j = 0; j < 4; ++j)
            aout[m * 768 + h * 64 + j * 16 + r] = f2b(oacc[j][reg] * inv);
    }
}

// ---------------------------------------------------------------------------
extern "C" void kernel_launch(void* const* d_in, const int* in_sizes, int n_in,
                              void* d_out, int out_size, void* d_ws, size_t ws_size,
                              hipStream_t stream) {
    const float* hs  = (const float*)d_in[0];
    const float* wq  = (const float*)d_in[1];
    const float* bq  = (const float*)d_in[2];
    const float* wk  = (const float*)d_in[3];
    const float* bk  = (const float*)d_in[4];
    const float* wv  = (const float*)d_in[5];
    const float* bv  = (const float*)d_in[6];
    const float* wo  = (const float*)d_in[7];
    const float* bo  = (const float*)d_in[8];
    const float* rph = (const float*)d_in[9];
    const float* rpw = (const float*)d_in[10];

    unsigned short* ws = (unsigned short*)d_ws;
    const int HS = 3145728, WN = 589824, RP = 8128;
    const int HB = 12 * 4096 * 64;
    unsigned short* hsb  = ws;
    unsigned short* wqb  = hsb  + HS;
    unsigned short* wkb  = wqb  + WN;
    unsigned short* wvb  = wkb  + WN;
    unsigned short* wob  = wvb  + WN;
    unsigned short* rphb = wob  + WN;
    unsigned short* rpwb = rphb + RP;
    unsigned short* qb   = rpwb + RP;          // q   [h][t][d]
    unsigned short* kb   = qb   + HB;          // k   [h][t][d]
    unsigned short* vtb  = kb   + HB;          // v^T [h][d][t], token-permuted
    unsigned short* rwb  = vtb  + HB;          // rel_w [h][t][kj]
    unsigned short* ab   = rwb  + HB;          // attn out [t][768]

    cvt_bf16<<<dim3((1380320 + 255) / 256), 256, 0, stream>>>(
        hs, wq, wk, wv, wo, rph, rpw, hsb);
    qkv128<<<dim3(6, 32, 3), 256, 0, stream>>>(
        hsb, wqb, wkb, wvb, bq, bk, bv, qb, kb, vtb);
    relw<<<dim3(64, 12), 256, 0, stream>>>(qb, rpwb, rwb);
    attn<<<dim3(64, 12), 256, 0, stream>>>(qb, kb, vtb, rphb, rwb, ab);
    out128<<<dim3(6, 32), 256, 0, stream>>>(ab, wob, bo, (float*)d_out);
}